// Round 4
// baseline (450.403 us; speedup 1.0000x reference)
//
#include <hip/hip_runtime.h>
#include <hip/hip_bf16.h>
#include <stdint.h>

// Problem (all fp32 I/O): out[m,o] = sum_k x[m,k] * qw[o,k] + bias[o]
//   qw = ternarize(weight): scale_o = max(max_k |w[o,k]|, 1e-6);
//   t = (w/scale > .5 ? 1 : w/scale < -.5 ? -1 : 0); qw = t*scale.
// Ternary t kept exact in bf16; fp32 scale applied in the GEMM epilogue.
// M=16384 (B*S), N=2048 (D_out), K=2048 (D_in).
//
// R4 changes vs R3:
//  - cvt_x_k pass DELETED. A (x) is staged into LDS as raw fp32 via
//    global_load_lds (16 B = 4 floats) and converted fp32->bf16 in registers
//    at frag-read time. Same RNE casts as before -> bit-identical numerics.
//  - A-tile LDS rows are 8 x 16B chunks, XOR-swizzled (slot c' holds global
//    chunk c'^(r&7)) so the 32-B frag reads stay 2-way-per-bank (free).
//  - ws shrinks to qw (8 MiB) + scales.
// R3 (kept): B-side XOR swizzle -> SQ_LDS_BANK_CONFLICT == 0.

#define M_DIM 16384
#define N_DIM 2048
#define K_DIM 2048

#define BM 128
#define BN 128
#define BK 32

typedef __bf16 bf16x8 __attribute__((ext_vector_type(8)));
typedef float f32x4 __attribute__((ext_vector_type(4)));

// ---------------------------------------------------------------------------
// Ternarize: per-row absmax scale + {-1,0,1} bf16 output. One block per row.
// ---------------------------------------------------------------------------
__global__ __launch_bounds__(256) void ternarize_k(
    const float* __restrict__ w,
    __hip_bfloat16* __restrict__ qw,
    float* __restrict__ scales) {
  const int row = blockIdx.x;
  const float* wr = w + (size_t)row * K_DIM;

  float m = 0.0f;
  for (int k = threadIdx.x; k < K_DIM; k += 256)
    m = fmaxf(m, fabsf(wr[k]));

  for (int off = 32; off > 0; off >>= 1)
    m = fmaxf(m, __shfl_down(m, off, 64));
  __shared__ float wmax[4];
  if ((threadIdx.x & 63) == 0) wmax[threadIdx.x >> 6] = m;
  __syncthreads();
  float scale = fmaxf(fmaxf(wmax[0], wmax[1]), fmaxf(wmax[2], wmax[3]));
  scale = fmaxf(scale, 1e-6f);
  if (threadIdx.x == 0) scales[row] = scale;

  for (int k = threadIdx.x; k < K_DIM; k += 256) {
    const float v = wr[k] / scale;  // identical fp32 op to the reference
    const float t = (v > 0.5f) ? 1.0f : ((v < -0.5f) ? -1.0f : 0.0f);
    qw[(size_t)row * K_DIM + k] = __float2bfloat16(t);
  }
}

// ---------------------------------------------------------------------------
// Fused GEMM: A = x [M,K] fp32 (converted in-register), B = qw [N,K] bf16.
// Block tile 128x128, BK=32, 4 waves (2x2), each wave 64x64 via 4x4 grid of
// 16x16x32 bf16 MFMAs. All staging via global_load_lds width=16.
// LDS: Asf 128x32 fp32 (16 KB, 8 chunks/row, swizzle c'^= r&7),
//      Bs  128x32 bf16 ( 8 KB, 4 chunks/row, swizzle c'^= (r>>1)&3).
// ---------------------------------------------------------------------------
static __device__ __forceinline__ void async_cp16(const void* g, void* l) {
  __builtin_amdgcn_global_load_lds(
      (__attribute__((address_space(1))) void*)const_cast<void*>(g),
      (__attribute__((address_space(3))) void*)(l), 16, 0, 0);
}

__global__ __launch_bounds__(256) void gemm_bt_k(
    const float* __restrict__ A,              // x   [M,K] fp32
    const __hip_bfloat16* __restrict__ B,     // qw  [N,K] bf16 ternary
    const float* __restrict__ scales,         // [N] fp32
    const float* __restrict__ bias,           // [N] fp32
    float* __restrict__ C) {                  // [M,N] fp32
  __shared__ float Asf[BM * BK];           // 16 KB
  __shared__ __hip_bfloat16 Bs[BN * BK];   //  8 KB

  const int tid = threadIdx.x;
  const int wave = tid >> 6;
  const int lane = tid & 63;
  const int quad = lane >> 4;
  const int lrow = lane & 15;
  const int wm = wave >> 1;
  const int wn = wave & 1;

  const int m0 = blockIdx.y * BM;
  const int n0 = blockIdx.x * BN;

  // --- staging assignments (all lane-contiguous LDS dests) ---
  // A: 1024 16-B chunks (128 rows x 8); thread owns L = tid + 256*s, s=0..3.
  //    LDS slot L -> row r=L>>3, slot col c'=L&7 holds global chunk c'^(r&7).
  const float* AgP[4];
  float* AsP[4];
  #pragma unroll
  for (int s = 0; s < 4; ++s) {
    const int L = tid + 256 * s;
    const int r = L >> 3;
    const int c = (L & 7) ^ (r & 7);
    AgP[s] = A + (size_t)(m0 + r) * K_DIM + c * 4;
    AsP[s] = Asf + (size_t)L * 4;
  }
  // B: 512 chunks (128 rows x 4); thread owns L = tid + 256*s, s=0..1.
  //    slot col c'=L&3 holds global chunk c'^((r>>1)&3).
  const __hip_bfloat16* BgP[2];
  __hip_bfloat16* BsP[2];
  #pragma unroll
  for (int s = 0; s < 2; ++s) {
    const int L = tid + 256 * s;
    const int r = L >> 2;
    const int c = (L & 3) ^ ((r >> 1) & 3);
    BgP[s] = B + (size_t)(n0 + r) * K_DIM + c * 8;
    BsP[s] = Bs + (size_t)L * 8;
  }

  // --- frag-read swizzle constants ---
  // A row R = wm*64 + i*16 + lrow -> R&7 == lrow&7 (i-independent).
  const int sA = lrow & 7;
  const int iloA = (2 * quad) ^ sA;  // LDS slot holding global chunk 2*quad
  const int ihiA = iloA ^ 1;         // LDS slot holding global chunk 2*quad+1
  // B row swizzle: (R>>1)&3 == (lrow>>1)&3.
  const int cB = ((quad ^ ((lrow >> 1) & 3))) * 8;

  f32x4 acc[4][4] = {};

  for (int kk = 0; kk < K_DIM; kk += BK) {
    __syncthreads();  // previous tile fully consumed
    #pragma unroll
    for (int s = 0; s < 4; ++s) async_cp16(AgP[s] + kk, AsP[s]);
    #pragma unroll
    for (int s = 0; s < 2; ++s) async_cp16(BgP[s] + kk, BsP[s]);
    __syncthreads();  // drains vmcnt(0) before s_barrier

    bf16x8 af[4], bfr[4];
    #pragma unroll
    for (int i = 0; i < 4; ++i) {
      const float* rowb = Asf + (wm * 64 + i * 16 + lrow) * BK;
      const f32x4 lo = *(const f32x4*)(rowb + iloA * 4);  // k = quad*8 .. +3
      const f32x4 hi = *(const f32x4*)(rowb + ihiA * 4);  // k = quad*8+4 .. +7
      bf16x8 f;
      f[0] = (__bf16)lo[0]; f[1] = (__bf16)lo[1];
      f[2] = (__bf16)lo[2]; f[3] = (__bf16)lo[3];
      f[4] = (__bf16)hi[0]; f[5] = (__bf16)hi[1];
      f[6] = (__bf16)hi[2]; f[7] = (__bf16)hi[3];
      af[i] = f;
    }
    #pragma unroll
    for (int i = 0; i < 4; ++i)
      bfr[i] = *(const bf16x8*)(Bs + (wn * 64 + i * 16 + lrow) * BK + cB);

    #pragma unroll
    for (int i = 0; i < 4; ++i)
      #pragma unroll
      for (int j = 0; j < 4; ++j)
        acc[i][j] = __builtin_amdgcn_mfma_f32_16x16x32_bf16(af[i], bfr[j], acc[i][j], 0, 0, 0);
  }

  // Epilogue: C/D layout col = lane&15, row = quad*4 + reg (16x16x32 bf16).
  #pragma unroll
  for (int j = 0; j < 4; ++j) {
    const int col = n0 + wn * 64 + j * 16 + lrow;
    const float s = scales[col];
    const float b = bias[col];
    #pragma unroll
    for (int i = 0; i < 4; ++i) {
      const int rbase = m0 + wm * 64 + i * 16 + quad * 4;
      #pragma unroll
      for (int r = 0; r < 4; ++r)
        C[(size_t)(rbase + r) * N_DIM + col] = acc[i][j][r] * s + b;
    }
  }
}

extern "C" void kernel_launch(void* const* d_in, const int* in_sizes, int n_in,
                              void* d_out, int out_size, void* d_ws, size_t ws_size,
                              hipStream_t stream) {
  const float* x    = (const float*)d_in[0];  // [4,4096,2048] fp32
  const float* w    = (const float*)d_in[1];  // [2048,2048]   fp32
  const float* bias = (const float*)d_in[2];  // [2048]        fp32
  float* out = (float*)d_out;                 // [16384,2048]  fp32

  // ws layout: qw bf16 [N*K] (8 MiB) | scales fp32 [N]
  __hip_bfloat16* qw = (__hip_bfloat16*)d_ws;
  float* scales = (float*)((char*)d_ws + (size_t)N_DIM * K_DIM * 2);

  ternarize_k<<<dim3(N_DIM), dim3(256), 0, stream>>>(w, qw, scales);
  gemm_bt_k<<<dim3(N_DIM / BN, M_DIM / BM), dim3(256), 0, stream>>>(x, qw, scales, bias, out);
}